// Round 4
// baseline (187.829 us; speedup 1.0000x reference)
//
#include <hip/hip_runtime.h>
#include <hip/hip_bf16.h>
#include <math.h>

// ScaledDotProductAttention, masked_softmax semantics (clip ±15, mask-mult,
// exp(x - max), re-mask, /(sum+1e-6)). B=16, L=2048, D=64, TEMP=8.
//
// Round-4: remove the __syncthreads() vmcnt(0) drain. Raw s_barrier +
// producer-side lgkmcnt(0) only -> prefetch loads stay in flight across
// barriers. Loads issued at TOP of each iteration (full iteration of slack
// before their ds_write consumes them). Two-pass fixed-shift softmax (M'=15),
// double-buffered swizzled LDS tiles, packed mask cache, XCD remap.

typedef __bf16 bf16x8v __attribute__((ext_vector_type(8)));
typedef __bf16 bf16x4v __attribute__((ext_vector_type(4)));
typedef __bf16 bf16x2v __attribute__((ext_vector_type(2)));
typedef float  f32x4   __attribute__((ext_vector_type(4)));
typedef int    i32x4   __attribute__((ext_vector_type(4)));

#define B_  16
#define L_  2048
#define D_  64
#define NKC 32

// swizzled byte offset within a [rows][64] bf16 tile (128 B per row)
__device__ __forceinline__ int swz(int row, int colb) {
    return (row * 128 + colb) ^ ((row & 7) << 4);
}

// barrier WITHOUT the vmcnt(0) drain: ds_writes must be visible to other
// waves (lgkmcnt(0)); global prefetch loads stay in flight.
__device__ __forceinline__ void bar() {
    asm volatile("s_waitcnt lgkmcnt(0)" ::: "memory");
    __builtin_amdgcn_s_barrier();
}

__global__ __launch_bounds__(256, 2)
void sdpa_kernel(const float* __restrict__ qg,
                 const float* __restrict__ kg,
                 const float* __restrict__ vg,
                 const int*   __restrict__ mg,
                 float* __restrict__ outg,    // [B][L][D]
                 float* __restrict__ attng)   // [B][L][L]
{
    __shared__ __align__(16) char KtB[2][8192];   // K tile bf16 [64][64] swz
    __shared__ __align__(16) char VtB[2][8192];   // V^T tile bf16 [d][k] swz
    __shared__ __align__(16) char PwB[4][2048];   // per-wave P [16][64] swz
    __shared__ unsigned short Ml[NKC][256];       // mask bits [kc][thread]

    const int t  = threadIdx.x;
    const int w  = t >> 6;
    const int l  = t & 63;
    const int lq = l & 15;        // q within wave tile (MFMA col / A row)
    const int g  = l >> 4;        // 4-lane group

    // XCD-grouping remap: 512 blocks = 8 XCDs x 64; XCD x gets batches 2x,2x+1
    const int bid  = blockIdx.x;
    const int virt = (bid & 7) * 64 + (bid >> 3);
    const int b  = virt >> 5;
    const int q0 = (virt & 31) * 64;
    const int qi = q0 + w * 16 + lq;

    const size_t kvbase = (size_t)b * (L_ * D_);
    const size_t mrow   = ((size_t)b * L_ + qi) * L_;

    // ---- Q fragments (B operand), 1/8 temperature folded in ----
    bf16x8v qf0, qf1;
    {
        const float* qrow = qg + ((size_t)b * L_ + qi) * D_;
        const f32x4* p0 = (const f32x4*)(qrow + g * 8);
        const f32x4* p1 = (const f32x4*)(qrow + 32 + g * 8);
        f32x4 x0 = p0[0], x1 = p0[1], x2 = p1[0], x3 = p1[1];
        #pragma unroll
        for (int j = 0; j < 4; ++j) {
            qf0[j]     = (__bf16)(x0[j] * 0.125f);
            qf0[4 + j] = (__bf16)(x1[j] * 0.125f);
            qf1[j]     = (__bf16)(x2[j] * 0.125f);
            qf1[4 + j] = (__bf16)(x3[j] * 0.125f);
        }
    }

    // ---- staging geometry ----
    const int sr  = t >> 2;               // K-tile row this thread stages
    const int scb = (t & 3) * 32;         // byte col (16 bf16 = 32 B)
    const float* kbase  = kg + kvbase + (size_t)sr * D_ + (t & 3) * 16;
    const float* vbase0 = vg + kvbase + (size_t)(2 * (t & 31)) * D_ + (t >> 5) * 8;
    const int dg = t >> 5, kp = t & 31;

    auto loadK = [&](int kc, f32x4& a, f32x4& bb, f32x4& c, f32x4& d) {
        const f32x4* s = (const f32x4*)(kbase + (size_t)kc * (64 * D_));
        a = s[0]; bb = s[1]; c = s[2]; d = s[3];
    };
    auto writeK = [&](char* buf, f32x4 a, f32x4 bb, f32x4 c, f32x4 d) {
        bf16x8v h0, h1;
        #pragma unroll
        for (int j = 0; j < 4; ++j) {
            h0[j] = (__bf16)a[j]; h0[4 + j] = (__bf16)bb[j];
            h1[j] = (__bf16)c[j]; h1[4 + j] = (__bf16)d[j];
        }
        *(bf16x8v*)(buf + swz(sr, scb))      = h0;
        *(bf16x8v*)(buf + swz(sr, scb + 16)) = h1;
    };
    auto loadV = [&](int kc, f32x4& a, f32x4& bb, f32x4& c, f32x4& d) {
        const float* r0 = vbase0 + (size_t)kc * (64 * D_);
        const f32x4* s0 = (const f32x4*)r0;
        const f32x4* s1 = (const f32x4*)(r0 + D_);
        a = s0[0]; bb = s0[1]; c = s1[0]; d = s1[1];
    };
    auto writeV = [&](char* buf, f32x4 a, f32x4 bb, f32x4 c, f32x4 d) {
        #pragma unroll
        for (int j = 0; j < 4; ++j) {
            bf16x2v p0; p0[0] = (__bf16)a[j];  p0[1] = (__bf16)c[j];
            *(bf16x2v*)(buf + swz(dg * 8 + j, kp * 4)) = p0;
            bf16x2v p1; p1[0] = (__bf16)bb[j]; p1[1] = (__bf16)d[j];
            *(bf16x2v*)(buf + swz(dg * 8 + 4 + j, kp * 4)) = p1;
        }
    };
    auto loadM = [&](int kc, i32x4& m0, i32x4& m1, i32x4& m2, i32x4& m3) {
        const int* p = mg + mrow + kc * 64 + g * 4;
        m0 = *(const i32x4*)(p);
        m1 = *(const i32x4*)(p + 16);
        m2 = *(const i32x4*)(p + 32);
        m3 = *(const i32x4*)(p + 48);
    };

    float rS = 0.f;
    float inv = 0.f;

    auto compute1 = [&](const char* KB, int kc, i32x4 m0, i32x4 m1, i32x4 m2, i32x4 m3) {
        unsigned mbits = 0;
        float part = 0.f;
        #pragma unroll
        for (int sub = 0; sub < 4; ++sub) {
            bf16x8v a0 = *(const bf16x8v*)(KB + swz(sub * 16 + lq, g * 16));
            bf16x8v a1 = *(const bf16x8v*)(KB + swz(sub * 16 + lq, 64 + g * 16));
            f32x4 s = {0.f, 0.f, 0.f, 0.f};
            s = __builtin_amdgcn_mfma_f32_16x16x32_bf16(a0, qf0, s, 0, 0, 0);
            s = __builtin_amdgcn_mfma_f32_16x16x32_bf16(a1, qf1, s, 0, 0, 0);
            i32x4 mv = (sub == 0) ? m0 : (sub == 1) ? m1 : (sub == 2) ? m2 : m3;
            #pragma unroll
            for (int r = 0; r < 4; ++r) {
                bool mm = (mv[r] != 0);
                mbits |= mm ? (1u << (sub * 4 + r)) : 0u;
                float y = mm ? (fminf(fmaxf(s[r], -15.f), 15.f) - 15.f) : -1e30f;
                part += __expf(y);        // exp(-1e30) = 0
            }
        }
        rS += part;
        Ml[kc][t] = (unsigned short)mbits;
    };

    f32x4 acc[4];
    #pragma unroll
    for (int i = 0; i < 4; ++i) acc[i] = (f32x4){0.f, 0.f, 0.f, 0.f};

    auto compute2 = [&](const char* KB, const char* VB, int kc) {
        const unsigned mbits = Ml[kc][t];
        #pragma unroll
        for (int sub = 0; sub < 4; ++sub) {
            bf16x8v a0 = *(const bf16x8v*)(KB + swz(sub * 16 + lq, g * 16));
            bf16x8v a1 = *(const bf16x8v*)(KB + swz(sub * 16 + lq, 64 + g * 16));
            f32x4 s = {0.f, 0.f, 0.f, 0.f};
            s = __builtin_amdgcn_mfma_f32_16x16x32_bf16(a0, qf0, s, 0, 0, 0);
            s = __builtin_amdgcn_mfma_f32_16x16x32_bf16(a1, qf1, s, 0, 0, 0);
            f32x4 pv; bf16x4v pb;
            #pragma unroll
            for (int r = 0; r < 4; ++r) {
                bool mm = (mbits >> (sub * 4 + r)) & 1u;
                float y = mm ? (fminf(fmaxf(s[r], -15.f), 15.f) - 15.f) : -1e30f;
                float p = __expf(y) * inv;
                pv[r] = p; pb[r] = (__bf16)p;
            }
            *(f32x4*)(attng + mrow + kc * 64 + sub * 16 + g * 4) = pv;
            *(bf16x4v*)(PwB[w] + swz(lq, (sub * 16 + g * 4) * 2)) = pb;
        }
        #pragma unroll
        for (int ks = 0; ks < 2; ++ks) {
            bf16x8v pa = *(const bf16x8v*)(PwB[w] + swz(lq, ks * 64 + g * 16));
            #pragma unroll
            for (int dt = 0; dt < 4; ++dt) {
                bf16x8v vb = *(const bf16x8v*)(VB + swz(dt * 16 + lq, ks * 64 + g * 16));
                acc[dt] = __builtin_amdgcn_mfma_f32_16x16x32_bf16(pa, vb, acc[dt], 0, 0, 0);
            }
        }
    };

    // prefetch register sets (A = even tiles, B = odd tiles)
    f32x4 kA0, kA1, kA2, kA3, kB0, kB1, kB2, kB3;
    f32x4 vA0, vA1, vA2, vA3, vB0, vB1, vB2, vB3;
    i32x4 mA0, mA1, mA2, mA3, mB0, mB1, mB2, mB3;

    // ======================= PASS 1: masked exp-sum =======================
    loadK(0, kA0, kA1, kA2, kA3);
    loadM(0, mA0, mA1, mA2, mA3);
    writeK(KtB[0], kA0, kA1, kA2, kA3);      // one-time stall
    loadK(1, kB0, kB1, kB2, kB3);
    loadM(1, mB0, mB1, mB2, mB3);
    bar();
    #pragma unroll 1
    for (int kc = 0; kc < NKC; kc += 2) {
        // even: loads at TOP (consumed next iter), compute buf0/tile kc
        { int kn = (kc + 2 < NKC) ? kc + 2 : NKC - 1; loadK(kn, kA0, kA1, kA2, kA3); }
        compute1(KtB[0], kc, mA0, mA1, mA2, mA3);
        { int kn = (kc + 2 < NKC) ? kc + 2 : NKC - 1; loadM(kn, mA0, mA1, mA2, mA3); }
        writeK(KtB[1], kB0, kB1, kB2, kB3);  // tile kc+1, loaded last iter
        bar();
        // odd: compute buf1/tile kc+1
        { int kn = (kc + 3 < NKC) ? kc + 3 : NKC - 1; loadK(kn, kB0, kB1, kB2, kB3); }
        compute1(KtB[1], kc + 1, mB0, mB1, mB2, mB3);
        { int kn = (kc + 3 < NKC) ? kc + 3 : NKC - 1; loadM(kn, mB0, mB1, mB2, mB3); }
        writeK(KtB[0], kA0, kA1, kA2, kA3);  // tile kc+2
        bar();
    }

    // issue pass-2 first tiles, then reduce (overlap load latency)
    loadK(0, kA0, kA1, kA2, kA3);
    loadV(0, vA0, vA1, vA2, vA3);
    rS += __shfl_xor(rS, 16, 64);
    rS += __shfl_xor(rS, 32, 64);
    inv = 1.f / (rS + 1e-6f);

    // ======================= PASS 2: attn + PV =======================
    writeK(KtB[0], kA0, kA1, kA2, kA3);
    writeV(VtB[0], vA0, vA1, vA2, vA3);
    loadK(1, kB0, kB1, kB2, kB3);
    loadV(1, vB0, vB1, vB2, vB3);
    bar();
    #pragma unroll 1
    for (int kc = 0; kc < NKC; kc += 2) {
        { int kn = (kc + 2 < NKC) ? kc + 2 : NKC - 1;
          loadK(kn, kA0, kA1, kA2, kA3); loadV(kn, vA0, vA1, vA2, vA3); }
        compute2(KtB[0], VtB[0], kc);
        writeK(KtB[1], kB0, kB1, kB2, kB3);
        writeV(VtB[1], vB0, vB1, vB2, vB3);
        bar();
        { int kn = (kc + 3 < NKC) ? kc + 3 : NKC - 1;
          loadK(kn, kB0, kB1, kB2, kB3); loadV(kn, vB0, vB1, vB2, vB3); }
        compute2(KtB[1], VtB[1], kc + 1);
        writeK(KtB[0], kA0, kA1, kA2, kA3);
        writeV(VtB[0], vA0, vA1, vA2, vA3);
        bar();
    }

    // epilogue: acc row = q-local (g*4+r), col = d (dt*16+lq)
    #pragma unroll
    for (int dt = 0; dt < 4; ++dt) {
        #pragma unroll
        for (int r = 0; r < 4; ++r) {
            outg[((size_t)b * L_ + (q0 + w * 16 + g * 4 + r)) * D_ + dt * 16 + lq] = acc[dt][r];
        }
    }
}

extern "C" void kernel_launch(void* const* d_in, const int* in_sizes, int n_in,
                              void* d_out, int out_size, void* d_ws, size_t ws_size,
                              hipStream_t stream) {
    (void)in_sizes; (void)n_in; (void)out_size; (void)d_ws; (void)ws_size;
    const float* q = (const float*)d_in[0];
    const float* k = (const float*)d_in[1];
    const float* v = (const float*)d_in[2];
    const int*   m = (const int*)d_in[3];
    float* out  = (float*)d_out;
    float* attn = out + (size_t)B_ * L_ * D_;
    dim3 grid(B_ * (L_ / 64));   // 512
    dim3 block(256);
    hipLaunchKernelGGL(sdpa_kernel, grid, block, 0, stream, q, k, v, m, out, attn);
}